// Round 2
// baseline (1054.105 us; speedup 1.0000x reference)
//
#include <hip/hip_runtime.h>
#include <hip/hip_bf16.h>

#define T_DIM 2048
#define B_DIM 32
#define CIN   80
#define H_DIM 256
#define TT    32               // t-tile per conv block
#define NTB   (T_DIM / TT)     // 64
#define NBLK  (B_DIM * NTB)    // 2048 conv blocks

typedef unsigned short u16;

// ---- workspace byte offsets ----
// [0,64)            : int flag (isbf)
// [64, ...)         : PS (NBLK*H f64), PQ (NBLK*H f64), PAR (768 f64), WT (61440 f64)
// [Y_OFF, ...)      : Y, f64 or f32 depending on tier
#define PS_OFF  ((size_t)64)
#define PQ_OFF  (PS_OFF + (size_t)NBLK * H_DIM * 8)            // 4,194,368
#define PAR_OFF (PQ_OFF + (size_t)NBLK * H_DIM * 8)            // 8,388,672
#define WT_OFF  (PAR_OFF + (size_t)768 * 8)                    // 8,394,816
#define Y_OFF   (WT_OFF + (size_t)H_DIM * CIN * 3 * 8)         // 8,886,336
#define Y_ELEMS ((size_t)T_DIM * B_DIM * H_DIM)                // 16,777,216

__device__ __forceinline__ double bf2d(u16 u) {
    union { unsigned int i; float f; } cv;
    cv.i = ((unsigned int)u) << 16;
    return (double)cv.f;
}

// load input element i as f64, interpreting buffer per flag
__device__ __forceinline__ double ld_in(const void* p, int i, int isbf) {
    if (isbf) return bf2d(((const u16*)p)[i]);
    return (double)((const float*)p)[i];
}

// ---- kernel 0: detect input dtype (bf16 vs f32) from x's bit patterns ----
__global__ __launch_bounds__(256) void k_detect(const u16* __restrict__ x,
                                                int* __restrict__ flag) {
    __shared__ int cnt[256];
    const int tid = threadIdx.x;
    int c = 0;
    for (int j = 0; j < 8; j++) {
        u16 u = x[tid * 8 + j];
        int e = (u >> 7) & 0xFF;
        if ((u & 0x7FFF) == 0 || (e >= 97 && e <= 157)) c++;  // |v| in [2^-30,2^30] or 0
    }
    cnt[tid] = c;
    __syncthreads();
    for (int off = 128; off > 0; off >>= 1) {
        if (tid < off) cnt[tid] += cnt[tid + off];
        __syncthreads();
    }
    if (tid == 0) flag[0] = (cnt[0] >= 1639) ? 1 : 0;  // bf16 ~100%, f32 ~62%
}

// ---- kernel 1: transpose conv_w (H,Cin,3) -> wt[(ci*3+k)][h] f64 ----
__global__ __launch_bounds__(256) void k_wprep(const void* __restrict__ w,
                                               const int* __restrict__ flag,
                                               double* __restrict__ wt) {
    const int isbf = flag[0];
    int idx = blockIdx.x * 256 + threadIdx.x;
    if (idx < H_DIM * CIN * 3) {
        int h = idx / (CIN * 3);
        int r = idx - h * (CIN * 3);
        wt[(size_t)r * H_DIM + h] = ld_in(w, idx, isbf);
    }
}

// ---- kernel 2: conv1d k=3 pad=1 + bias (f64), y in (T,B,H); partial BN sums ----
template <typename YT>
__global__ __launch_bounds__(256) void k_conv(const void* __restrict__ x,
                                              const void* __restrict__ bias,
                                              const int* __restrict__ flag,
                                              const double* __restrict__ wt,
                                              YT* __restrict__ y,
                                              double* __restrict__ ps,
                                              double* __restrict__ pq) {
    __shared__ double xs[CIN * (TT + 2)];  // xs[ci*(TT+2)+tl], tl=0 -> t0-1
    const int isbf = flag[0];
    const int tb = blockIdx.x;
    const int b  = blockIdx.y;
    const int h  = threadIdx.x;
    const int t0 = tb * TT;

    for (int idx = threadIdx.x; idx < CIN * (TT + 2); idx += 256) {
        int tl = idx / CIN;
        int ci = idx - tl * CIN;
        int tg = t0 - 1 + tl;
        double v = 0.0;
        if (tg >= 0 && tg < T_DIM) v = ld_in(x, (b * T_DIM + tg) * CIN + ci, isbf);
        xs[ci * (TT + 2) + tl] = v;
    }
    __syncthreads();

    double acc[TT];
    const double bv = ld_in(bias, h, isbf);
#pragma unroll
    for (int i = 0; i < TT; i++) acc[i] = bv;

    for (int ci = 0; ci < CIN; ci++) {
        const double* wr = wt + (size_t)(ci * 3) * H_DIM + h;
        const double w0 = wr[0], w1 = wr[H_DIM], w2 = wr[2 * H_DIM];
        const double* xr = xs + ci * (TT + 2);
        double x0 = xr[0], x1 = xr[1];
#pragma unroll
        for (int tt = 0; tt < TT; tt++) {
            double x2 = xr[tt + 2];
            acc[tt] = fma(w2, x2, fma(w1, x1, fma(w0, x0, acc[tt])));
            x0 = x1; x1 = x2;
        }
    }

    double s1 = 0.0, s2 = 0.0;
#pragma unroll
    for (int tt = 0; tt < TT; tt++) {
        y[((size_t)(t0 + tt) * B_DIM + b) * H_DIM + h] = (YT)acc[tt];
        s1 += acc[tt];
        s2 += acc[tt] * acc[tt];
    }
    const int blk = b * NTB + tb;
    ps[(size_t)blk * H_DIM + h] = s1;
    pq[(size_t)blk * H_DIM + h] = s2;
}

// ---- kernel 3: reduce BN stats per channel, fold affine ----
__global__ __launch_bounds__(256) void k_stats(const double* __restrict__ ps,
                                               const double* __restrict__ pq,
                                               const void* __restrict__ gamma,
                                               const void* __restrict__ beta,
                                               const int* __restrict__ flag,
                                               double* __restrict__ par) {
    __shared__ double l1[256], l2[256];
    const int isbf = flag[0];
    const int h = blockIdx.x, tid = threadIdx.x;
    double s1 = 0.0, s2 = 0.0;
    for (int j = tid; j < NBLK; j += 256) {
        s1 += ps[(size_t)j * H_DIM + h];
        s2 += pq[(size_t)j * H_DIM + h];
    }
    l1[tid] = s1; l2[tid] = s2;
    __syncthreads();
    for (int off = 128; off > 0; off >>= 1) {
        if (tid < off) { l1[tid] += l1[tid + off]; l2[tid] += l2[tid + off]; }
        __syncthreads();
    }
    if (tid == 0) {
        const double N = (double)T_DIM * (double)B_DIM;
        double mean = l1[0] / N;
        double var  = l2[0] / N - mean * mean;
        double r    = 1.0 / sqrt(var + 1e-5);
        par[h]       = mean;
        par[256 + h] = r * ld_in(gamma, h, isbf);  // folded scale
        par[512 + h] = ld_in(beta, h, isbf);
    }
}

// ---- kernel 4: EXACT sequential LIF, one thread per (b,h), 16-deep pipeline ----
// grid (16 hg, 8 bg), 64 threads: h = hg*16 + (tid&15), b = bg*4 + (tid>>4)
template <typename YT>
__global__ __launch_bounds__(64) void k_lif(const YT* __restrict__ y,
                                            const double* __restrict__ par,
                                            const int* __restrict__ flag,
                                            void* __restrict__ out) {
    const int isbf = flag[0];
    const int h = blockIdx.x * 16 + (threadIdx.x & 15);
    const int b = blockIdx.y * 4 + (threadIdx.x >> 4);

    const double m  = par[h];
    const double A  = par[256 + h];
    const double be = par[512 + h];

    const size_t base = (size_t)b * H_DIM + h;
    const size_t ST   = (size_t)B_DIM * H_DIM;
    const YT* yb = y + base;
    u16*   ob16 = (u16*)out + base;
    float* ob32 = (float*)out + base;

    double v = 0.0;
    YT r[16];
#pragma unroll
    for (int j = 0; j < 16; j++) r[j] = yb[(size_t)j * ST];

    for (int t = 0; t < T_DIM; t += 16) {
#pragma unroll
        for (int j = 0; j < 16; j++) {
            double val = fma((double)r[j] - m, A, be);   // BN affine
            int tn = t + 16 + j;
            if (tn < T_DIM) r[j] = yb[(size_t)tn * ST];  // prefetch (indep of v)
            v = fma(v, 0.5, val);                        // v*decay + input
            bool sp = (v - 1.0) >= 0.0;                  // spike(v - VTH)
            size_t oi = (size_t)(t + j) * ST;
            if (isbf) ob16[oi] = sp ? (u16)0x3F80 : (u16)0;
            else      ob32[oi] = sp ? 1.0f : 0.0f;
            v = sp ? 0.0 : v;                            // hard reset
        }
    }
}

// ---- diagnostic: ws too small ----
__global__ void k_code(u16* out, float code) {
    if (threadIdx.x == 0 && blockIdx.x == 0) {
        union { unsigned int i; float f; } cv; cv.f = code;
        out[0] = (u16)(cv.i >> 16);
    }
}

extern "C" void kernel_launch(void* const* d_in, const int* in_sizes, int n_in,
                              void* d_out, int out_size, void* d_ws, size_t ws_size,
                              hipStream_t stream) {
    const void* x     = d_in[0];  // (B,T,Cin)
    const void* w     = d_in[1];  // (H,Cin,3)
    const void* cb    = d_in[2];  // (H,)
    const void* gamma = d_in[3];  // (H,)
    const void* beta  = d_in[4];  // (H,)

    char* wsb   = (char*)d_ws;
    int* flag   = (int*)wsb;
    double* PS  = (double*)(wsb + PS_OFF);
    double* PQ  = (double*)(wsb + PQ_OFF);
    double* PAR = (double*)(wsb + PAR_OFF);
    double* WT  = (double*)(wsb + WT_OFF);
    void* Yp    = (void*)(wsb + Y_OFF);

    const size_t need64 = Y_OFF + Y_ELEMS * 8;  // 143,104,064
    const size_t need32 = Y_OFF + Y_ELEMS * 4;  //  75,995,200

    if (ws_size < need32) {
        // can't run: signal via code 1000 at out[0]
        hipMemsetAsync(d_out, 0, (size_t)out_size * 2, stream);
        k_code<<<1, 64, 0, stream>>>((u16*)d_out, 1000.0f);
        return;
    }

    k_detect<<<1, 256, 0, stream>>>((const u16*)x, flag);
    k_wprep<<<dim3((H_DIM * CIN * 3 + 255) / 256), dim3(256), 0, stream>>>(w, flag, WT);

    if (ws_size >= need64) {
        k_conv<double><<<dim3(NTB, B_DIM), dim3(256), 0, stream>>>(
            x, cb, flag, WT, (double*)Yp, PS, PQ);
        k_stats<<<dim3(H_DIM), dim3(256), 0, stream>>>(PS, PQ, gamma, beta, flag, PAR);
        k_lif<double><<<dim3(16, 8), dim3(64), 0, stream>>>(
            (const double*)Yp, PAR, flag, d_out);
    } else {
        k_conv<float><<<dim3(NTB, B_DIM), dim3(256), 0, stream>>>(
            x, cb, flag, WT, (float*)Yp, PS, PQ);
        k_stats<<<dim3(H_DIM), dim3(256), 0, stream>>>(PS, PQ, gamma, beta, flag, PAR);
        k_lif<float><<<dim3(16, 8), dim3(64), 0, stream>>>(
            (const float*)Yp, PAR, flag, d_out);
    }
}

// Round 3
// 328.743 us; speedup vs baseline: 3.2065x; 3.2065x over previous
//
#include <hip/hip_runtime.h>
#include <hip/hip_bf16.h>

#define T_DIM 2048
#define B_DIM 32
#define CIN   80
#define H_DIM 256
#define TT    32               // t-tile per conv block
#define NTB   (T_DIM / TT)     // 64
#define NBLK  (B_DIM * NTB)    // 2048 conv blocks

// LIF chunking: bitwise resync via hard reset during warm-up (see R2 analysis)
#define CHUNKS 32
#define CLEN  (T_DIM / CHUNKS) // 64
#define WARM  128

typedef unsigned short u16;

// ---- workspace byte offsets ----
#define PS_OFF  ((size_t)64)
#define PQ_OFF  (PS_OFF + (size_t)NBLK * H_DIM * 8)            // 4,194,368
#define PAR_OFF (PQ_OFF + (size_t)NBLK * H_DIM * 8)            // 8,388,672
#define WT_OFF  (PAR_OFF + (size_t)768 * 8)                    // 8,394,816
#define Y_OFF   (WT_OFF + (size_t)H_DIM * CIN * 3 * 8)         // 8,886,336
#define Y_ELEMS ((size_t)T_DIM * B_DIM * H_DIM)                // 16,777,216

__device__ __forceinline__ double bf2d(u16 u) {
    union { unsigned int i; float f; } cv;
    cv.i = ((unsigned int)u) << 16;
    return (double)cv.f;
}

__device__ __forceinline__ double ld_in(const void* p, int i, int isbf) {
    if (isbf) return bf2d(((const u16*)p)[i]);
    return (double)((const float*)p)[i];
}

// ---- kernel 0: detect input dtype (bf16 vs f32) from x's bit patterns ----
__global__ __launch_bounds__(256) void k_detect(const u16* __restrict__ x,
                                                int* __restrict__ flag) {
    __shared__ int cnt[256];
    const int tid = threadIdx.x;
    int c = 0;
    for (int j = 0; j < 8; j++) {
        u16 u = x[tid * 8 + j];
        int e = (u >> 7) & 0xFF;
        if ((u & 0x7FFF) == 0 || (e >= 97 && e <= 157)) c++;
    }
    cnt[tid] = c;
    __syncthreads();
    for (int off = 128; off > 0; off >>= 1) {
        if (tid < off) cnt[tid] += cnt[tid + off];
        __syncthreads();
    }
    if (tid == 0) flag[0] = (cnt[0] >= 1639) ? 1 : 0;
}

// ---- kernel 1: transpose conv_w (H,Cin,3) -> wt[(ci*3+k)*H + h] f64 ----
__global__ __launch_bounds__(256) void k_wprep(const void* __restrict__ w,
                                               const int* __restrict__ flag,
                                               double* __restrict__ wt) {
    const int isbf = flag[0];
    int idx = blockIdx.x * 256 + threadIdx.x;
    if (idx < H_DIM * CIN * 3) {
        int h = idx / (CIN * 3);
        int r = idx - h * (CIN * 3);
        wt[(size_t)r * H_DIM + h] = ld_in(w, idx, isbf);
    }
}

// ---- kernel 2: conv1d k=3 pad=1 + bias (f64), y (T,B,H); partial BN sums ----
// w loads pipelined one ci ahead; x read as double2 pairs from LDS.
template <typename YT>
__global__ __launch_bounds__(256) void k_conv(const void* __restrict__ x,
                                              const void* __restrict__ bias,
                                              const int* __restrict__ flag,
                                              const double* __restrict__ wt,
                                              YT* __restrict__ y,
                                              double* __restrict__ ps,
                                              double* __restrict__ pq) {
    __shared__ double xs[CIN * (TT + 2)];  // xs[ci*(TT+2)+tl], tl=0 -> t0-1
    const int isbf = flag[0];
    const int tb = blockIdx.x;
    const int b  = blockIdx.y;
    const int h  = threadIdx.x;
    const int t0 = tb * TT;

    for (int idx = threadIdx.x; idx < CIN * (TT + 2); idx += 256) {
        int tl = idx / CIN;
        int ci = idx - tl * CIN;
        int tg = t0 - 1 + tl;
        double v = 0.0;
        if (tg >= 0 && tg < T_DIM) v = ld_in(x, (b * T_DIM + tg) * CIN + ci, isbf);
        xs[ci * (TT + 2) + tl] = v;
    }
    __syncthreads();

    double acc[TT];
    const double bv = ld_in(bias, h, isbf);
#pragma unroll
    for (int i = 0; i < TT; i++) acc[i] = bv;

    const double* wp = wt + h;
    double w0 = wp[0], w1 = wp[H_DIM], w2 = wp[2 * H_DIM];
    for (int ci = 0; ci < CIN; ci++) {
        // prefetch next ci's weights (hide global latency behind 48 FMAs)
        double wn0 = 0.0, wn1 = 0.0, wn2 = 0.0;
        if (ci + 1 < CIN) {
            const double* wq = wt + (size_t)(ci + 1) * 3 * H_DIM + h;
            wn0 = wq[0]; wn1 = wq[H_DIM]; wn2 = wq[2 * H_DIM];
        }
        const double* xr = xs + ci * (TT + 2);
        double x0 = xr[0], x1 = xr[1];
#pragma unroll
        for (int tt = 0; tt < TT; tt += 2) {
            double2 xp = *(const double2*)(xr + tt + 2);  // 16B-aligned: ci*34+tt+2 even
            acc[tt]     = fma(w2, xp.x, fma(w1, x1,   fma(w0, x0, acc[tt])));
            acc[tt + 1] = fma(w2, xp.y, fma(w1, xp.x, fma(w0, x1, acc[tt + 1])));
            x0 = xp.x; x1 = xp.y;
        }
        w0 = wn0; w1 = wn1; w2 = wn2;
    }

    double s1 = 0.0, s2 = 0.0;
#pragma unroll
    for (int tt = 0; tt < TT; tt++) {
        y[((size_t)(t0 + tt) * B_DIM + b) * H_DIM + h] = (YT)acc[tt];
        s1 += acc[tt];
        s2 += acc[tt] * acc[tt];
    }
    const int blk = b * NTB + tb;
    ps[(size_t)blk * H_DIM + h] = s1;
    pq[(size_t)blk * H_DIM + h] = s2;
}

// ---- kernel 3: reduce BN stats per channel, fold affine ----
__global__ __launch_bounds__(256) void k_stats(const double* __restrict__ ps,
                                               const double* __restrict__ pq,
                                               const void* __restrict__ gamma,
                                               const void* __restrict__ beta,
                                               const int* __restrict__ flag,
                                               double* __restrict__ par) {
    __shared__ double l1[256], l2[256];
    const int isbf = flag[0];
    const int h = blockIdx.x, tid = threadIdx.x;
    double s1 = 0.0, s2 = 0.0;
    for (int j = tid; j < NBLK; j += 256) {
        s1 += ps[(size_t)j * H_DIM + h];
        s2 += pq[(size_t)j * H_DIM + h];
    }
    l1[tid] = s1; l2[tid] = s2;
    __syncthreads();
    for (int off = 128; off > 0; off >>= 1) {
        if (tid < off) { l1[tid] += l1[tid + off]; l2[tid] += l2[tid + off]; }
        __syncthreads();
    }
    if (tid == 0) {
        const double N = (double)T_DIM * (double)B_DIM;
        double mean = l1[0] / N;
        double var  = l2[0] / N - mean * mean;
        double r    = 1.0 / sqrt(var + 1e-5);
        par[h]       = mean;
        par[256 + h] = r * ld_in(gamma, h, isbf);
        par[512 + h] = ld_in(beta, h, isbf);
    }
}

// ---- kernel 4: chunked LIF, warm-up resync; bitwise-matching fma sequence ----
// grid (CHUNKS, B), 256 threads = h. Ops identical to R2's exact kernel.
template <typename YT>
__global__ __launch_bounds__(256) void k_lif(const YT* __restrict__ y,
                                             const double* __restrict__ par,
                                             const int* __restrict__ flag,
                                             void* __restrict__ out) {
    const int isbf = flag[0];
    const int c = blockIdx.x, b = blockIdx.y, h = threadIdx.x;
    const int t_out = c * CLEN;
    int t_begin = t_out - WARM; if (t_begin < 0) t_begin = 0;
    const int t_end = t_out + CLEN;

    const double m  = par[h];
    const double A  = par[256 + h];
    const double be = par[512 + h];

    const size_t base = (size_t)b * H_DIM + h;
    const size_t ST   = (size_t)B_DIM * H_DIM;
    const YT* yb = y + base;
    u16*   ob16 = (u16*)out + base;
    float* ob32 = (float*)out + base;

    double v = 0.0;
    YT b0[8], b1[8];
#pragma unroll
    for (int j = 0; j < 8; j++) b0[j] = yb[(size_t)(t_begin + j) * ST];

    const int nb = (t_end - t_begin) / 8;  // 8, 16, or 24 — always exact
    int t = t_begin;
    for (int ib = 0; ib < nb; ++ib) {
        const int tn = (ib + 1 < nb) ? (t + 8) : t_begin;  // last prefetch: dummy
#pragma unroll
        for (int j = 0; j < 8; j++) b1[j] = yb[(size_t)(tn + j) * ST];
#pragma unroll
        for (int j = 0; j < 8; j++) {
            double val = fma((double)b0[j] - m, A, be);   // BN affine
            v = fma(v, 0.5, val);                         // v*decay + input
            bool sp = (v - 1.0) >= 0.0;                   // spike(v - VTH)
            if (t + j >= t_out) {
                size_t oi = (size_t)(t + j) * ST;
                if (isbf) ob16[oi] = sp ? (u16)0x3F80 : (u16)0;
                else      ob32[oi] = sp ? 1.0f : 0.0f;
            }
            v = sp ? 0.0 : v;                             // hard reset
        }
#pragma unroll
        for (int j = 0; j < 8; j++) b0[j] = b1[j];
        t += 8;
    }
}

// ---- diagnostic: ws too small ----
__global__ void k_code(u16* out, float code) {
    if (threadIdx.x == 0 && blockIdx.x == 0) {
        union { unsigned int i; float f; } cv; cv.f = code;
        out[0] = (u16)(cv.i >> 16);
    }
}

extern "C" void kernel_launch(void* const* d_in, const int* in_sizes, int n_in,
                              void* d_out, int out_size, void* d_ws, size_t ws_size,
                              hipStream_t stream) {
    const void* x     = d_in[0];
    const void* w     = d_in[1];
    const void* cb    = d_in[2];
    const void* gamma = d_in[3];
    const void* beta  = d_in[4];

    char* wsb   = (char*)d_ws;
    int* flag   = (int*)wsb;
    double* PS  = (double*)(wsb + PS_OFF);
    double* PQ  = (double*)(wsb + PQ_OFF);
    double* PAR = (double*)(wsb + PAR_OFF);
    double* WT  = (double*)(wsb + WT_OFF);
    void* Yp    = (void*)(wsb + Y_OFF);

    const size_t need64 = Y_OFF + Y_ELEMS * 8;  // 143,104,064
    const size_t need32 = Y_OFF + Y_ELEMS * 4;  //  75,995,200

    if (ws_size < need32) {
        hipMemsetAsync(d_out, 0, (size_t)out_size * 2, stream);
        k_code<<<1, 64, 0, stream>>>((u16*)d_out, 1000.0f);
        return;
    }

    k_detect<<<1, 256, 0, stream>>>((const u16*)x, flag);
    k_wprep<<<dim3((H_DIM * CIN * 3 + 255) / 256), dim3(256), 0, stream>>>(w, flag, WT);

    if (ws_size >= need64) {
        k_conv<double><<<dim3(NTB, B_DIM), dim3(256), 0, stream>>>(
            x, cb, flag, WT, (double*)Yp, PS, PQ);
        k_stats<<<dim3(H_DIM), dim3(256), 0, stream>>>(PS, PQ, gamma, beta, flag, PAR);
        k_lif<double><<<dim3(CHUNKS, B_DIM), dim3(256), 0, stream>>>(
            (const double*)Yp, PAR, flag, d_out);
    } else {
        k_conv<float><<<dim3(NTB, B_DIM), dim3(256), 0, stream>>>(
            x, cb, flag, WT, (float*)Yp, PS, PQ);
        k_stats<<<dim3(H_DIM), dim3(256), 0, stream>>>(PS, PQ, gamma, beta, flag, PAR);
        k_lif<float><<<dim3(CHUNKS, B_DIM), dim3(256), 0, stream>>>(
            (const float*)Yp, PAR, flag, d_out);
    }
}

// Round 4
// 325.498 us; speedup vs baseline: 3.2384x; 1.0100x over previous
//
#include <hip/hip_runtime.h>
#include <hip/hip_bf16.h>

#define T_DIM 2048
#define B_DIM 32
#define CIN   80
#define H_DIM 256
#define TT    16               // t-tile per conv block: acc[16] = 32 VGPRs, stays in VGPRs
#define NTB   (T_DIM / TT)     // 128
#define NBLK  (B_DIM * NTB)    // 4096 conv blocks

// LIF chunking: bitwise resync via hard reset during warm-up (R2/R3 verified absmax=0)
#define CHUNKS 16
#define CLEN  (T_DIM / CHUNKS) // 128
#define WARM  96

typedef unsigned short u16;

// ---- workspace byte offsets ----
#define PS_OFF  ((size_t)64)
#define PQ_OFF  (PS_OFF + (size_t)NBLK * H_DIM * 8)
#define PAR_OFF (PQ_OFF + (size_t)NBLK * H_DIM * 8)
#define WT_OFF  (PAR_OFF + (size_t)768 * 8)
#define Y_OFF   (WT_OFF + (size_t)H_DIM * CIN * 3 * 8)
#define Y_ELEMS ((size_t)T_DIM * B_DIM * H_DIM)                // 16,777,216

__device__ __forceinline__ double bf2d(u16 u) {
    union { unsigned int i; float f; } cv;
    cv.i = ((unsigned int)u) << 16;
    return (double)cv.f;
}

__device__ __forceinline__ double ld_in(const void* p, int i, int isbf) {
    if (isbf) return bf2d(((const u16*)p)[i]);
    return (double)((const float*)p)[i];
}

// ---- kernel 0: detect input dtype (bf16 vs f32) from x's bit patterns ----
__global__ __launch_bounds__(256) void k_detect(const u16* __restrict__ x,
                                                int* __restrict__ flag) {
    __shared__ int cnt[256];
    const int tid = threadIdx.x;
    int c = 0;
    for (int j = 0; j < 8; j++) {
        u16 u = x[tid * 8 + j];
        int e = (u >> 7) & 0xFF;
        if ((u & 0x7FFF) == 0 || (e >= 97 && e <= 157)) c++;
    }
    cnt[tid] = c;
    __syncthreads();
    for (int off = 128; off > 0; off >>= 1) {
        if (tid < off) cnt[tid] += cnt[tid + off];
        __syncthreads();
    }
    if (tid == 0) flag[0] = (cnt[0] >= 1639) ? 1 : 0;
}

// ---- kernel 1: transpose conv_w (H,Cin,3) -> wt[(ci*3+k)*H + h] f64 ----
__global__ __launch_bounds__(256) void k_wprep(const void* __restrict__ w,
                                               const int* __restrict__ flag,
                                               double* __restrict__ wt) {
    const int isbf = flag[0];
    int idx = blockIdx.x * 256 + threadIdx.x;
    if (idx < H_DIM * CIN * 3) {
        int h = idx / (CIN * 3);
        int r = idx - h * (CIN * 3);
        wt[(size_t)r * H_DIM + h] = ld_in(w, idx, isbf);
    }
}

// ---- kernel 2: conv1d k=3 pad=1 + bias (f64), y (T,B,H); partial BN sums ----
// TT=16 so acc[] fits VGPRs (no AGPR shuffling). w pipelined one ci ahead.
template <typename YT>
__global__ __launch_bounds__(256) void k_conv(const void* __restrict__ x,
                                              const void* __restrict__ bias,
                                              const int* __restrict__ flag,
                                              const double* __restrict__ wt,
                                              YT* __restrict__ y,
                                              double* __restrict__ ps,
                                              double* __restrict__ pq) {
    __shared__ __align__(16) double xs[CIN * (TT + 2)];  // xs[ci*(TT+2)+tl], tl=0 -> t0-1
    const int isbf = flag[0];
    const int tb = blockIdx.x;
    const int b  = blockIdx.y;
    const int h  = threadIdx.x;
    const int t0 = tb * TT;

    for (int idx = threadIdx.x; idx < CIN * (TT + 2); idx += 256) {
        int tl = idx / CIN;
        int ci = idx - tl * CIN;
        int tg = t0 - 1 + tl;
        double v = 0.0;
        if (tg >= 0 && tg < T_DIM) v = ld_in(x, (b * T_DIM + tg) * CIN + ci, isbf);
        xs[ci * (TT + 2) + tl] = v;
    }
    __syncthreads();

    double acc[TT];
    const double bv = ld_in(bias, h, isbf);
#pragma unroll
    for (int i = 0; i < TT; i++) acc[i] = bv;

    const double* wp = wt + h;
    double w0 = wp[0], w1 = wp[H_DIM], w2 = wp[2 * H_DIM];
    for (int ci = 0; ci < CIN; ci++) {
        // prefetch next ci's weights (hidden behind 48 f64 FMAs)
        double wn0 = 0.0, wn1 = 0.0, wn2 = 0.0;
        if (ci + 1 < CIN) {
            const double* wq = wt + (size_t)(ci + 1) * 3 * H_DIM + h;
            wn0 = wq[0]; wn1 = wq[H_DIM]; wn2 = wq[2 * H_DIM];
        }
        const double* xr = xs + ci * (TT + 2);
        double x0 = xr[0], x1 = xr[1];
#pragma unroll
        for (int tt = 0; tt < TT; tt += 2) {
            double2 xp = *(const double2*)(xr + tt + 2);  // (TT+2)=18 even, tt even -> 16B ok
            acc[tt]     = fma(w2, xp.x, fma(w1, x1,   fma(w0, x0, acc[tt])));
            acc[tt + 1] = fma(w2, xp.y, fma(w1, xp.x, fma(w0, x1, acc[tt + 1])));
            x0 = xp.x; x1 = xp.y;
        }
        w0 = wn0; w1 = wn1; w2 = wn2;
    }

    double s1 = 0.0, s2 = 0.0;
#pragma unroll
    for (int tt = 0; tt < TT; tt++) {
        y[((size_t)(t0 + tt) * B_DIM + b) * H_DIM + h] = (YT)acc[tt];
        s1 += acc[tt];
        s2 = fma(acc[tt], acc[tt], s2);
    }
    const int blk = b * NTB + tb;
    ps[(size_t)blk * H_DIM + h] = s1;
    pq[(size_t)blk * H_DIM + h] = s2;
}

// ---- kernel 3: reduce BN stats per channel, fold affine ----
__global__ __launch_bounds__(256) void k_stats(const double* __restrict__ ps,
                                               const double* __restrict__ pq,
                                               const void* __restrict__ gamma,
                                               const void* __restrict__ beta,
                                               const int* __restrict__ flag,
                                               double* __restrict__ par) {
    __shared__ double l1[256], l2[256];
    const int isbf = flag[0];
    const int h = blockIdx.x, tid = threadIdx.x;
    double s1 = 0.0, s2 = 0.0;
    for (int j = tid; j < NBLK; j += 256) {
        s1 += ps[(size_t)j * H_DIM + h];
        s2 += pq[(size_t)j * H_DIM + h];
    }
    l1[tid] = s1; l2[tid] = s2;
    __syncthreads();
    for (int off = 128; off > 0; off >>= 1) {
        if (tid < off) { l1[tid] += l1[tid + off]; l2[tid] += l2[tid + off]; }
        __syncthreads();
    }
    if (tid == 0) {
        const double N = (double)T_DIM * (double)B_DIM;
        double mean = l1[0] / N;
        double var  = l2[0] / N - mean * mean;
        double r    = 1.0 / sqrt(var + 1e-5);
        par[h]       = mean;
        par[256 + h] = r * ld_in(gamma, h, isbf);
        par[512 + h] = ld_in(beta, h, isbf);
    }
}

// ---- kernel 4: chunked LIF, warm-up resync, 16-deep prefetch ----
// grid (CHUNKS, B), 256 threads = h. fma sequence identical to R2's exact kernel.
template <typename YT>
__global__ __launch_bounds__(256) void k_lif(const YT* __restrict__ y,
                                             const double* __restrict__ par,
                                             const int* __restrict__ flag,
                                             void* __restrict__ out) {
    const int isbf = flag[0];
    const int c = blockIdx.x, b = blockIdx.y, h = threadIdx.x;
    const int t_out = c * CLEN;
    int t_begin = t_out - WARM; if (t_begin < 0) t_begin = 0;
    const int t_end = t_out + CLEN;

    const double m  = par[h];
    const double A  = par[256 + h];
    const double be = par[512 + h];

    const size_t base = (size_t)b * H_DIM + h;
    const size_t ST   = (size_t)B_DIM * H_DIM;
    const YT* yb = y + base;
    u16*   ob16 = (u16*)out + base;
    float* ob32 = (float*)out + base;

    double v = 0.0;
    YT b0[16], b1[16];
#pragma unroll
    for (int j = 0; j < 16; j++) b0[j] = yb[(size_t)(t_begin + j) * ST];

    const int nb = (t_end - t_begin) / 16;  // 8 (chunk 0) or 14 — always exact
    int t = t_begin;
    for (int ib = 0; ib < nb; ++ib) {
        const int tn = (ib + 1 < nb) ? (t + 16) : t_begin;  // last prefetch: dummy
#pragma unroll
        for (int j = 0; j < 16; j++) b1[j] = yb[(size_t)(tn + j) * ST];
#pragma unroll
        for (int j = 0; j < 16; j++) {
            double val = fma((double)b0[j] - m, A, be);   // BN affine
            v = fma(v, 0.5, val);                         // v*decay + input
            bool sp = (v - 1.0) >= 0.0;                   // spike(v - VTH)
            if (t + j >= t_out) {
                size_t oi = (size_t)(t + j) * ST;
                if (isbf) ob16[oi] = sp ? (u16)0x3F80 : (u16)0;
                else      ob32[oi] = sp ? 1.0f : 0.0f;
            }
            v = sp ? 0.0 : v;                             // hard reset
        }
#pragma unroll
        for (int j = 0; j < 16; j++) b0[j] = b1[j];
        t += 16;
    }
}

// ---- diagnostic: ws too small ----
__global__ void k_code(u16* out, float code) {
    if (threadIdx.x == 0 && blockIdx.x == 0) {
        union { unsigned int i; float f; } cv; cv.f = code;
        out[0] = (u16)(cv.i >> 16);
    }
}

extern "C" void kernel_launch(void* const* d_in, const int* in_sizes, int n_in,
                              void* d_out, int out_size, void* d_ws, size_t ws_size,
                              hipStream_t stream) {
    const void* x     = d_in[0];
    const void* w     = d_in[1];
    const void* cb    = d_in[2];
    const void* gamma = d_in[3];
    const void* beta  = d_in[4];

    char* wsb   = (char*)d_ws;
    int* flag   = (int*)wsb;
    double* PS  = (double*)(wsb + PS_OFF);
    double* PQ  = (double*)(wsb + PQ_OFF);
    double* PAR = (double*)(wsb + PAR_OFF);
    double* WT  = (double*)(wsb + WT_OFF);
    void* Yp    = (void*)(wsb + Y_OFF);

    const size_t need64 = Y_OFF + Y_ELEMS * 8;
    const size_t need32 = Y_OFF + Y_ELEMS * 4;

    if (ws_size < need32) {
        hipMemsetAsync(d_out, 0, (size_t)out_size * 2, stream);
        k_code<<<1, 64, 0, stream>>>((u16*)d_out, 1000.0f);
        return;
    }

    k_detect<<<1, 256, 0, stream>>>((const u16*)x, flag);
    k_wprep<<<dim3((H_DIM * CIN * 3 + 255) / 256), dim3(256), 0, stream>>>(w, flag, WT);

    if (ws_size >= need64) {
        k_conv<double><<<dim3(NTB, B_DIM), dim3(256), 0, stream>>>(
            x, cb, flag, WT, (double*)Yp, PS, PQ);
        k_stats<<<dim3(H_DIM), dim3(256), 0, stream>>>(PS, PQ, gamma, beta, flag, PAR);
        k_lif<double><<<dim3(CHUNKS, B_DIM), dim3(256), 0, stream>>>(
            (const double*)Yp, PAR, flag, d_out);
    } else {
        k_conv<float><<<dim3(NTB, B_DIM), dim3(256), 0, stream>>>(
            x, cb, flag, WT, (float*)Yp, PS, PQ);
        k_stats<<<dim3(H_DIM), dim3(256), 0, stream>>>(PS, PQ, gamma, beta, flag, PAR);
        k_lif<float><<<dim3(CHUNKS, B_DIM), dim3(256), 0, stream>>>(
            (const float*)Yp, PAR, flag, d_out);
    }
}

// Round 5
// 309.933 us; speedup vs baseline: 3.4011x; 1.0502x over previous
//
#include <hip/hip_runtime.h>
#include <hip/hip_bf16.h>

#define T_DIM 2048
#define B_DIM 32
#define CIN   80
#define H_DIM 256
#define TT    16               // t-tile per conv block
#define NTB   (T_DIM / TT)     // 128
#define NBLK  (B_DIM * NTB)    // 4096 conv blocks

// LIF chunking (warm-up resync; residual <= 2^-48 -> flip prob ~1e-7)
#define CHUNKS 16
#define CLEN  (T_DIM / CHUNKS) // 128
#define WARM  48
#define SEG   16               // timesteps per LDS staging segment

#define NPART 64               // stats partials
#define JPER  (NBLK / NPART)   // 64

typedef unsigned short u16;

// ---- workspace byte offsets (identical footprint to R4: need64 = 143,104,064 fits) ----
#define PS_OFF  ((size_t)64)
#define PQ_OFF  (PS_OFF + (size_t)NBLK * H_DIM * 8)
#define PAR_OFF (PQ_OFF + (size_t)NBLK * H_DIM * 8)
#define WT_OFF  (PAR_OFF + (size_t)768 * 8)
// PA/PB alias the WT region (weights consumed by k_conv before statsA runs)
#define PA_OFF  WT_OFF
#define PB_OFF  (WT_OFF + (size_t)NPART * H_DIM * 8)   // 131072 each; WT region = 491520 B
#define Y_OFF   (WT_OFF + (size_t)H_DIM * CIN * 3 * 8)
#define Y_ELEMS ((size_t)T_DIM * B_DIM * H_DIM)        // 16,777,216

__device__ __forceinline__ double bf2d(u16 u) {
    union { unsigned int i; float f; } cv;
    cv.i = ((unsigned int)u) << 16;
    return (double)cv.f;
}

__device__ __forceinline__ double ld_in(const void* p, int i, int isbf) {
    if (isbf) return bf2d(((const u16*)p)[i]);
    return (double)((const float*)p)[i];
}

// ---- kernel 0: detect input dtype (bf16 vs f32) ----
__global__ __launch_bounds__(256) void k_detect(const u16* __restrict__ x,
                                                int* __restrict__ flag) {
    __shared__ int cnt[256];
    const int tid = threadIdx.x;
    int c = 0;
    for (int j = 0; j < 8; j++) {
        u16 u = x[tid * 8 + j];
        int e = (u >> 7) & 0xFF;
        if ((u & 0x7FFF) == 0 || (e >= 97 && e <= 157)) c++;
    }
    cnt[tid] = c;
    __syncthreads();
    for (int off = 128; off > 0; off >>= 1) {
        if (tid < off) cnt[tid] += cnt[tid + off];
        __syncthreads();
    }
    if (tid == 0) flag[0] = (cnt[0] >= 1639) ? 1 : 0;
}

// ---- kernel 1: transpose conv_w (H,Cin,3) -> wt[(ci*3+k)*H + h] f64 ----
__global__ __launch_bounds__(256) void k_wprep(const void* __restrict__ w,
                                               const int* __restrict__ flag,
                                               double* __restrict__ wt) {
    const int isbf = flag[0];
    int idx = blockIdx.x * 256 + threadIdx.x;
    if (idx < H_DIM * CIN * 3) {
        int h = idx / (CIN * 3);
        int r = idx - h * (CIN * 3);
        wt[(size_t)r * H_DIM + h] = ld_in(w, idx, isbf);
    }
}

// ---- kernel 2: conv1d k=3 pad=1 + bias (f64), y (T,B,H); partial BN sums ----
// launch_bounds(256,4): 128-reg budget so acc[] stays in VGPRs (no accvgpr churn)
template <typename YT>
__global__ __launch_bounds__(256, 4) void k_conv(const void* __restrict__ x,
                                                 const void* __restrict__ bias,
                                                 const int* __restrict__ flag,
                                                 const double* __restrict__ wt,
                                                 YT* __restrict__ y,
                                                 double* __restrict__ ps,
                                                 double* __restrict__ pq) {
    __shared__ __align__(16) double xs[CIN * (TT + 2)];
    const int isbf = flag[0];
    const int tb = blockIdx.x;
    const int b  = blockIdx.y;
    const int h  = threadIdx.x;
    const int t0 = tb * TT;

    for (int idx = threadIdx.x; idx < CIN * (TT + 2); idx += 256) {
        int tl = idx / CIN;
        int ci = idx - tl * CIN;
        int tg = t0 - 1 + tl;
        double v = 0.0;
        if (tg >= 0 && tg < T_DIM) v = ld_in(x, (b * T_DIM + tg) * CIN + ci, isbf);
        xs[ci * (TT + 2) + tl] = v;
    }
    __syncthreads();

    double acc[TT];
    const double bv = ld_in(bias, h, isbf);
#pragma unroll
    for (int i = 0; i < TT; i++) acc[i] = bv;

    const double* wp = wt + h;
    double w0 = wp[0], w1 = wp[H_DIM], w2 = wp[2 * H_DIM];
    for (int ci = 0; ci < CIN; ci++) {
        double wn0 = 0.0, wn1 = 0.0, wn2 = 0.0;
        if (ci + 1 < CIN) {
            const double* wq = wt + (size_t)(ci + 1) * 3 * H_DIM + h;
            wn0 = wq[0]; wn1 = wq[H_DIM]; wn2 = wq[2 * H_DIM];
        }
        const double* xr = xs + ci * (TT + 2);
        double x0 = xr[0], x1 = xr[1];
#pragma unroll
        for (int tt = 0; tt < TT; tt += 2) {
            double2 xp = *(const double2*)(xr + tt + 2);
            acc[tt]     = fma(w2, xp.x, fma(w1, x1,   fma(w0, x0, acc[tt])));
            acc[tt + 1] = fma(w2, xp.y, fma(w1, xp.x, fma(w0, x1, acc[tt + 1])));
            x0 = xp.x; x1 = xp.y;
        }
        w0 = wn0; w1 = wn1; w2 = wn2;
    }

    double s1 = 0.0, s2 = 0.0;
#pragma unroll
    for (int tt = 0; tt < TT; tt++) {
        y[((size_t)(t0 + tt) * B_DIM + b) * H_DIM + h] = (YT)acc[tt];
        s1 += acc[tt];
        s2 = fma(acc[tt], acc[tt], s2);
    }
    const int blk = b * NTB + tb;
    ps[(size_t)blk * H_DIM + h] = s1;
    pq[(size_t)blk * H_DIM + h] = s2;
}

// ---- kernel 3a: partial reduce over j (coalesced: lanes span h) ----
__global__ __launch_bounds__(256) void k_statsA(const double* __restrict__ ps,
                                                const double* __restrict__ pq,
                                                double* __restrict__ pa,
                                                double* __restrict__ pb) {
    const int k = blockIdx.x, h = threadIdx.x;
    double s1 = 0.0, s2 = 0.0;
    const int j0 = k * JPER;
    for (int j = j0; j < j0 + JPER; j++) {
        s1 += ps[(size_t)j * H_DIM + h];
        s2 += pq[(size_t)j * H_DIM + h];
    }
    pa[(size_t)k * H_DIM + h] = s1;
    pb[(size_t)k * H_DIM + h] = s2;
}

// ---- kernel 3b: final reduce + fold BN affine ----
__global__ __launch_bounds__(256) void k_statsB(const double* __restrict__ pa,
                                                const double* __restrict__ pb,
                                                const void* __restrict__ gamma,
                                                const void* __restrict__ beta,
                                                const int* __restrict__ flag,
                                                double* __restrict__ par) {
    const int isbf = flag[0];
    const int h = threadIdx.x;
    double s1 = 0.0, s2 = 0.0;
    for (int k = 0; k < NPART; k++) {
        s1 += pa[(size_t)k * H_DIM + h];
        s2 += pb[(size_t)k * H_DIM + h];
    }
    const double N = (double)T_DIM * (double)B_DIM;
    double mean = s1 / N;
    double var  = s2 / N - mean * mean;
    double r    = 1.0 / sqrt(var + 1e-5);
    par[h]       = mean;
    par[256 + h] = r * ld_in(gamma, h, isbf);
    par[512 + h] = ld_in(beta, h, isbf);
}

// ---- kernel 4: chunked LIF, LDS double-buffered segments ----
// grid (CHUNKS, B), 256 threads = h. Global loads for seg s+1 issue before
// computing seg s from LDS -> latency exposed once per 32KB, not per step.
template <typename YT>
__global__ __launch_bounds__(256, 4) void k_lif(const YT* __restrict__ y,
                                                const double* __restrict__ par,
                                                const int* __restrict__ flag,
                                                void* __restrict__ out) {
    __shared__ YT buf[2][SEG * H_DIM];   // 2 x 32 KB (f64) -> 2 blocks/CU
    const int isbf = flag[0];
    const int c = blockIdx.x, b = blockIdx.y, h = threadIdx.x;
    const int t_out = c * CLEN;
    int t_begin = t_out - WARM; if (t_begin < 0) t_begin = 0;
    const int t_end = t_out + CLEN;
    const int nseg = (t_end - t_begin) / SEG;   // 8 (chunk 0) or 11

    const double m  = par[h];
    const double A  = par[256 + h];
    const double be = par[512 + h];

    const size_t ST = (size_t)B_DIM * H_DIM;
    const YT* yb = y + (size_t)b * H_DIM + h;
    u16*   ob16 = (u16*)out + (size_t)b * H_DIM + h;
    float* ob32 = (float*)out + (size_t)b * H_DIM + h;

    // prologue: stage segment 0
    {
        YT g[SEG];
#pragma unroll
        for (int k = 0; k < SEG; k++) g[k] = yb[(size_t)(t_begin + k) * ST];
#pragma unroll
        for (int k = 0; k < SEG; k++) buf[0][k * H_DIM + h] = g[k];
    }
    __syncthreads();

    double v = 0.0;
    for (int s = 0; s < nseg; s++) {
        const int cur = s & 1;
        const bool more = (s + 1 < nseg);
        YT g[SEG];
        if (more) {
            const int t1 = t_begin + (s + 1) * SEG;
#pragma unroll
            for (int k = 0; k < SEG; k++) g[k] = yb[(size_t)(t1 + k) * ST];
        }
        // bulk LDS->reg, then the recurrence (fma sequence identical to R2-R4)
        double r[SEG];
#pragma unroll
        for (int k = 0; k < SEG; k++) r[k] = (double)buf[cur][k * H_DIM + h];
        const int t0s = t_begin + s * SEG;
#pragma unroll
        for (int k = 0; k < SEG; k++) {
            double val = fma(r[k] - m, A, be);    // BN affine
            v = fma(v, 0.5, val);                 // v*decay + input
            bool sp = (v - 1.0) >= 0.0;           // spike(v - VTH)
            const int t = t0s + k;
            if (t >= t_out) {
                size_t oi = (size_t)t * ST;
                if (isbf) ob16[oi] = sp ? (u16)0x3F80 : (u16)0;
                else      ob32[oi] = sp ? 1.0f : 0.0f;
            }
            v = sp ? 0.0 : v;                     // hard reset
        }
        if (more) {
#pragma unroll
            for (int k = 0; k < SEG; k++) buf[cur ^ 1][k * H_DIM + h] = g[k];
        }
        __syncthreads();
    }
}

// ---- diagnostic: ws too small ----
__global__ void k_code(u16* out, float code) {
    if (threadIdx.x == 0 && blockIdx.x == 0) {
        union { unsigned int i; float f; } cv; cv.f = code;
        out[0] = (u16)(cv.i >> 16);
    }
}

extern "C" void kernel_launch(void* const* d_in, const int* in_sizes, int n_in,
                              void* d_out, int out_size, void* d_ws, size_t ws_size,
                              hipStream_t stream) {
    const void* x     = d_in[0];
    const void* w     = d_in[1];
    const void* cb    = d_in[2];
    const void* gamma = d_in[3];
    const void* beta  = d_in[4];

    char* wsb   = (char*)d_ws;
    int* flag   = (int*)wsb;
    double* PS  = (double*)(wsb + PS_OFF);
    double* PQ  = (double*)(wsb + PQ_OFF);
    double* PAR = (double*)(wsb + PAR_OFF);
    double* WT  = (double*)(wsb + WT_OFF);
    double* PA  = (double*)(wsb + PA_OFF);   // aliases WT (dead after k_conv)
    double* PB  = (double*)(wsb + PB_OFF);
    void* Yp    = (void*)(wsb + Y_OFF);

    const size_t need64 = Y_OFF + Y_ELEMS * 8;
    const size_t need32 = Y_OFF + Y_ELEMS * 4;

    if (ws_size < need32) {
        hipMemsetAsync(d_out, 0, (size_t)out_size * 2, stream);
        k_code<<<1, 64, 0, stream>>>((u16*)d_out, 1000.0f);
        return;
    }

    k_detect<<<1, 256, 0, stream>>>((const u16*)x, flag);
    k_wprep<<<dim3((H_DIM * CIN * 3 + 255) / 256), dim3(256), 0, stream>>>(w, flag, WT);

    if (ws_size >= need64) {
        k_conv<double><<<dim3(NTB, B_DIM), dim3(256), 0, stream>>>(
            x, cb, flag, WT, (double*)Yp, PS, PQ);
        k_statsA<<<dim3(NPART), dim3(256), 0, stream>>>(PS, PQ, PA, PB);
        k_statsB<<<dim3(1), dim3(256), 0, stream>>>(PA, PB, gamma, beta, flag, PAR);
        k_lif<double><<<dim3(CHUNKS, B_DIM), dim3(256), 0, stream>>>(
            (const double*)Yp, PAR, flag, d_out);
    } else {
        k_conv<float><<<dim3(NTB, B_DIM), dim3(256), 0, stream>>>(
            x, cb, flag, WT, (float*)Yp, PS, PQ);
        k_statsA<<<dim3(NPART), dim3(256), 0, stream>>>(PS, PQ, PA, PB);
        k_statsB<<<dim3(1), dim3(256), 0, stream>>>(PA, PB, gamma, beta, flag, PAR);
        k_lif<float><<<dim3(CHUNKS, B_DIM), dim3(256), 0, stream>>>(
            (const float*)Yp, PAR, flag, d_out);
    }
}